// Round 9
// baseline (682.127 us; speedup 1.0000x reference)
//
#include <hip/hip_runtime.h>
#include <hip/hip_bf16.h>
#include <stdint.h>

// Problem constants (MixtralAttention: B=2, S=2048, H=4096, 32 q-heads, 8 kv-heads, HD=128)
#define Hdim 4096
#define NH 32
#define NKV 8
#define HDs 128
#define Bb 2
#define Ss 2048
#define QKV_N 6144              // NH*HD + 2*NKV*HD
#define SCALEF 0.08838834764831845f   // 128^-0.5
#define LOG2E 1.4426950408889634f
// sliding window = 4096 >= S=2048  ->  pure causal mask

typedef __attribute__((ext_vector_type(4))) float f32x4;
typedef __attribute__((ext_vector_type(8))) short bf16x8;

__device__ __forceinline__ unsigned short f2bf(float f) {
  union { float f; unsigned u; } v; v.f = f;
  unsigned r = v.u + 0x7fffu + ((v.u >> 16) & 1u);   // RNE
  return (unsigned short)(r >> 16);
}
__device__ __forceinline__ float bf2f(unsigned short h) {
  union { unsigned u; float f; } v; v.u = ((unsigned)h) << 16;
  return v.f;
}
__device__ __forceinline__ unsigned cvtpk(float lo, float hi) {
  unsigned r;
  asm("v_cvt_pk_bf16_f32 %0, %1, %2" : "=v"(r) : "v"(lo), "v"(hi));
  return r;
}

#define GLOBAL_AS(p) ((const __attribute__((address_space(1))) void*)(p))
#define LDS_AS(p)    ((__attribute__((address_space(3))) void*)(p))

// ---------------- fp32 -> bf16 elementwise (hidden_states) ----------------
__global__ void k_f32_to_bf16(const float* __restrict__ src, unsigned short* __restrict__ dst, int n) {
  int i = (blockIdx.x * blockDim.x + threadIdx.x) * 4;
  if (i >= n) return;
  f32x4 v = *(const f32x4*)(src + i);
  uint2 o;
  o.x = (unsigned)f2bf(v.x) | ((unsigned)f2bf(v.y) << 16);
  o.y = (unsigned)f2bf(v.z) | ((unsigned)f2bf(v.w) << 16);
  *(uint2*)(dst + i) = o;
}

// ---------------- fp32 [K][N] -> bf16 [N][K] tile transpose (weights) ----------------
__global__ void k_transpose_bf16(const float* __restrict__ src, unsigned short* __restrict__ dst,
                                 int K, int N) {
  __shared__ unsigned short tile[32][33];
  int n0 = blockIdx.x * 32, k0 = blockIdx.y * 32;
  int tx = threadIdx.x, ty0 = threadIdx.y;
#pragma unroll
  for (int i = 0; i < 4; i++) {
    int ty = ty0 + i * 8;
    tile[ty][tx] = f2bf(src[(size_t)(k0 + ty) * N + n0 + tx]);
  }
  __syncthreads();
#pragma unroll
  for (int i = 0; i < 4; i++) {
    int ty = ty0 + i * 8;
    dst[(size_t)(n0 + ty) * K + k0 + tx] = tile[tx][ty];
  }
}

// ---------------- bf16 GEMM v3: 2 blocks/CU, fat wave tiles, minimal barriers ----------
// C[M][N] = A[M][K]*Bt[N][K]^T.  BK=32, 256 thr = 4 waves (2M x 2N), wave tile
// (BM/2)x(BN/2).  Double-buffered LDS = 2*(BM+BN)*64B = 48 KB; ~210 VGPR ->
// 2 blocks/CU (r8 lesson: 1 block/CU lockstep leaves MFMA pipe idle during
// read/drain phases; cross-block overlap hides them -- m114).  One barrier per
// K-tile: stage(kt+1) -> frag reads (compiler emits fine-grained lgkmcnt) ->
// 32 MFMA -> __syncthreads() (its vmcnt(0) drain is REQUIRED for the DMA->ds_read
// dependency; co-resident block covers the stall).  64B rows make l4-slot frag
// reads inherently bank-conflict-free: no swizzle, fully linear staging.
template <int OUT_BF16, int BM, int BN>
__global__ __launch_bounds__(256, 2) void k_gemmv3(const unsigned short* __restrict__ A,
                                                   const unsigned short* __restrict__ Bt,
                                                   void* __restrict__ C,
                                                   int M, int N, int K, int nbn) {
  constexpr int MR = BM / 32;              // m-frags per wave
  constexpr int NR = BN / 32;              // n-frags per wave
  __shared__ __align__(16) unsigned short As[2][BM * 32];
  __shared__ __align__(16) unsigned short Bs[2][BN * 32];

  int nwg = gridDim.x;
  int orig = blockIdx.x;
  int wg = (orig & 7) * (nwg >> 3) + (orig >> 3);   // XCD swizzle (nwg % 8 == 0)
  int bm = wg / nbn, bn = wg % nbn;

  int t = threadIdx.x, w = t >> 6, lane = t & 63;
  int wm = w >> 1, wn = w & 1;             // 2M x 2N waves
  int l15 = lane & 15, l4 = lane >> 4;

  const unsigned short* Ag = A + (size_t)(bm * BM) * K;
  const unsigned short* Bg = Bt + (size_t)(bn * BN) * K;
  int NKT = K >> 5;

  f32x4 zero = {0.f, 0.f, 0.f, 0.f};
  f32x4 acc[MR][NR];
#pragma unroll
  for (int m = 0; m < MR; m++)
#pragma unroll
    for (int n = 0; n < NR; n++) acc[m][n] = zero;

  // staging: one global_load_lds = 256 thr x 16 B = 4 KB = 64 rows x 64 B (linear).
  int srow = t >> 2;          // row-in-inst 0..63
  int sk = (t & 3) * 8;       // k-slot offset (elements)
  auto stage = [&](int d, int kt) {
#pragma unroll
    for (int i = 0; i < BM / 64; i++)
      __builtin_amdgcn_global_load_lds(
          GLOBAL_AS(Ag + (size_t)(i * 64 + srow) * K + kt * 32 + sk),
          LDS_AS(&As[d][i * 2048 + w * 512]), 16, 0, 0);
#pragma unroll
    for (int i = 0; i < BN / 64; i++)
      __builtin_amdgcn_global_load_lds(
          GLOBAL_AS(Bg + (size_t)(i * 64 + srow) * K + kt * 32 + sk),
          LDS_AS(&Bs[d][i * 2048 + w * 512]), 16, 0, 0);
  };

  stage(0, 0);
  __syncthreads();

  for (int kt = 0; kt < NKT; kt++) {
    int d = kt & 1;
    if (kt + 1 < NKT) stage(d ^ 1, kt + 1);   // DMA issues early; lands by tile end
    // frag reads (plain LDS loads -> compiler fine-grained lgkmcnt before each use)
    bf16x8 a[MR], b[NR];
#pragma unroll
    for (int m = 0; m < MR; m++) {
      int row = wm * (BM / 2) + m * 16 + l15;
      a[m] = *(const bf16x8*)&As[d][row * 32 + l4 * 8];
    }
#pragma unroll
    for (int n = 0; n < NR; n++) {
      int row = wn * (BN / 2) + n * 16 + l15;
      b[n] = *(const bf16x8*)&Bs[d][row * 32 + l4 * 8];
    }
    __builtin_amdgcn_s_setprio(1);
#pragma unroll
    for (int m = 0; m < MR; m++)
#pragma unroll
      for (int n = 0; n < NR; n++)
        acc[m][n] = __builtin_amdgcn_mfma_f32_16x16x32_bf16(a[m], b[n], acc[m][n], 0, 0, 0);
    __builtin_amdgcn_s_setprio(0);
    __syncthreads();   // drains vmcnt(0): kt+1 landed; all reads of buf d done
  }

  // epilogue: C/D layout col=lane&15, row=(lane>>4)*4+reg  [verified m89/m91]
#pragma unroll
  for (int m = 0; m < MR; m++)
#pragma unroll
    for (int n = 0; n < NR; n++) {
      int col = bn * BN + wn * (BN / 2) + n * 16 + l15;
#pragma unroll
      for (int r = 0; r < 4; r++) {
        int row = bm * BM + wm * (BM / 2) + m * 16 + l4 * 4 + r;
        float v = acc[m][n][r];
        if (OUT_BF16)
          ((unsigned short*)C)[(size_t)row * N + col] = f2bf(v);
        else
          ((float*)C)[(size_t)row * N + col] = v;
      }
    }
}

// ---------------- RoPE (interleaved pairs) in-place on bf16 qkv ------------
__global__ void k_rope(unsigned short* __restrict__ qkv, const int* __restrict__ pos) {
  int bs = blockIdx.y;                       // b*S + s
  int t = threadIdx.x;                       // 256
  int head = blockIdx.x * 4 + (t >> 6);      // 0..39 (0-31 q, 32-39 k)
  int p = t & 63;                            // pair index
  int col;
  float scale;
  if (head < NH) { col = head * HDs + 2 * p; scale = SCALEF * LOG2E; }
  else           { col = NH * HDs + (head - NH) * HDs + 2 * p; scale = 1.f; }
  size_t idx = (size_t)bs * QKV_N + col;
  float x0 = bf2f(qkv[idx]), x1 = bf2f(qkv[idx + 1]);
  float position = (float)pos[bs];
  float inv_freq = exp2f((float)p * -0.2076205059304601f);
  float ang = position * inv_freq;
  float sv, cv;
  sincosf(ang, &sv, &cv);
  float o0 = (x0 * cv - x1 * sv) * scale;
  float o1 = (x1 * cv + x0 * sv) * scale;
  qkv[idx]     = f2bf(o0);
  qkv[idx + 1] = f2bf(o1);
}

// ---------------- V repack: qkv v-part [s][d] -> vt[b][kv][d][s_perm] ---------
__global__ void k_vt(const unsigned short* __restrict__ qkv, unsigned short* __restrict__ vt) {
  __shared__ unsigned short tile[32][33];
  int bkv = blockIdx.z;                 // b*NKV + kvh
  int d0 = blockIdx.y * 32;
  int s0 = blockIdx.x * 32;
  int b = bkv >> 3, kvh = bkv & 7;
  int tx = threadIdx.x, ty0 = threadIdx.y;
  const unsigned short* src = qkv + (size_t)b * Ss * QKV_N + NH * HDs + NKV * HDs + kvh * HDs;
#pragma unroll
  for (int i = 0; i < 4; i++) {
    int ty = ty0 + i * 8;
    tile[ty][tx] = src[(size_t)(s0 + ty) * QKV_N + d0 + tx];
  }
  __syncthreads();
  unsigned short* dst = vt + (size_t)bkv * HDs * Ss;
  int c = s0 + tx;
  int o = c & 63;
  int pcol = (c & ~63) | ((o & 32) | ((o & 12) << 1) | ((o & 16) >> 2) | (o & 3));
#pragma unroll
  for (int i = 0; i < 4; i++) {
    int ty = ty0 + i * 8;
    dst[(size_t)(d0 + ty) * Ss + pcol] = tile[tx][ty];
  }
}

// ---------------- Flash attention v5 (r7, unchanged) -------------------------------
__global__ __launch_bounds__(512, 4) void k_attn(const unsigned short* __restrict__ qkv,
                                                 const unsigned short* __restrict__ vt,
                                                 unsigned short* __restrict__ out) {
  __shared__ __align__(16) unsigned short Ks[2][64 * 128];   // 32 KB
  __shared__ __align__(16) unsigned short Vs[2][128 * 64];   // 32 KB

  int bid = blockIdx.x;
  int qc = 15 - (bid & 15);     // LPT: heavy blocks first
  int h = (bid >> 4) & 31;
  int b = bid >> 9;
  int kvh = h >> 2;             // GROUP = 4
  int t = threadIdx.x;
  int w = t >> 6, lane = t & 63;
  int l15 = lane & 15, l4 = lane >> 4;
  int qb0 = qc * 128;
  int qw = qb0 + w * 16;        // this wave's 16 q rows

  const unsigned short* kbase = qkv + (size_t)b * Ss * QKV_N + NH * HDs + (size_t)kvh * HDs;
  const unsigned short* vbase = vt + ((size_t)(b * NKV + kvh)) * HDs * Ss;

  bf16x8 qf[4];
#pragma unroll
  for (int ch = 0; ch < 4; ch++)
    qf[ch] = *(const bf16x8*)&qkv[((size_t)(b * Ss) + qw + l15) * QKV_N +
                                  (size_t)h * HDs + ch * 32 + l4 * 8];

  f32x4 zero = {0.f, 0.f, 0.f, 0.f};
  f32x4 acc[8];
#pragma unroll
  for (int dt = 0; dt < 8; dt++) acc[dt] = zero;
  float mrun = -1e30f, lsum = 0.f;

  int nkv = qc * 2 + 2;

  auto stageK = [&](int bufi, int kv_) {
#pragma unroll
    for (int i2 = 0; i2 < 2; i2++) {
      int row = i2 * 32 + (t >> 4);
      int sl = (t & 15) ^ (row & 7);
      __builtin_amdgcn_global_load_lds(GLOBAL_AS(kbase + (size_t)(kv_ + row) * QKV_N + sl * 8),
                                       LDS_AS(&Ks[bufi][i2 * 4096 + w * 512]), 16, 0, 0);
    }
  };
  auto stageV = [&](int bufi, int kv_) {
#pragma unroll
    for (int i2 = 0; i2 < 2; i2++) {
      int row = i2 * 64 + (t >> 3);
      int sl = (t & 7) ^ (row & 7);
      __builtin_amdgcn_global_load_lds(GLOBAL_AS(vbase + (size_t)row * Ss + kv_ + sl * 8),
                                       LDS_AS(&Vs[bufi][i2 * 4096 + w * 512]), 16, 0, 0);
    }
  };

  stageK(0, 0); stageV(0, 0);
  for (int it = 0; it < nkv; it++) {
    int kvb = it * 64;
    bool more = (it + 1 < nkv);
    if (more) {
      stageK((it + 1) & 1, kvb + 64);
      stageV((it + 1) & 1, kvb + 64);
      asm volatile("s_waitcnt vmcnt(4)" ::: "memory");
    } else {
      asm volatile("s_waitcnt vmcnt(0)" ::: "memory");
    }
    __builtin_amdgcn_s_barrier();

    if (kvb <= qw + 15) {
      const unsigned short* Kb = Ks[it & 1];
      const unsigned short* Vb = Vs[it & 1];

      f32x4 sacc[4];
#pragma unroll
      for (int kt2 = 0; kt2 < 4; kt2++) sacc[kt2] = zero;
#pragma unroll
      for (int kt2 = 0; kt2 < 4; kt2++) {
        int row = kt2 * 16 + l15;
#pragma unroll
        for (int ch = 0; ch < 4; ch++) {
          int ps = (ch * 4 + l4) ^ (row & 7);
          bf16x8 kf = *(const bf16x8*)&Kb[row * 128 + ps * 8];
          sacc[kt2] = __builtin_amdgcn_mfma_f32_16x16x32_bf16(kf, qf[ch], sacc[kt2], 0, 0, 0);
        }
      }

      int qi = qw + l15;
      bool fullvis = (kvb + 63 <= qw);
      float pv[16];
      float tmax = -1e30f;
#pragma unroll
      for (int kt2 = 0; kt2 < 4; kt2++)
#pragma unroll
        for (int r = 0; r < 4; r++) {
          int kvi = kvb + kt2 * 16 + l4 * 4 + r;
          float v = sacc[kt2][r];
          if (!fullvis) v = (kvi <= qi) ? v : -1e30f;
          pv[kt2 * 4 + r] = v;
          tmax = fmaxf(tmax, v);
        }
      tmax = fmaxf(tmax, __shfl_xor(tmax, 16));
      tmax = fmaxf(tmax, __shfl_xor(tmax, 32));
      if (!__all(tmax - mrun <= 8.f)) {
        float mnew = fmaxf(mrun, tmax);
        float fsc = exp2f(mrun - mnew);
        mrun = mnew;
        lsum *= fsc;
        float fr[4];
#pragma unroll
        for (int r = 0; r < 4; r++) fr[r] = __shfl(fsc, l4 * 4 + r);
#pragma unroll
        for (int dt = 0; dt < 8; dt++)
#pragma unroll
          for (int r = 0; r < 4; r++) acc[dt][r] *= fr[r];
      }
      float rs = 0.f;
#pragma unroll
      for (int i = 0; i < 16; i++) {
        pv[i] = exp2f(pv[i] - mrun);
        rs += pv[i];
      }
      rs += __shfl_xor(rs, 16);
      rs += __shfl_xor(rs, 32);
      lsum += rs;

      bf16x8 pa[2];
      {
        union { unsigned u[4]; bf16x8 v8; } pk0, pk1;
#pragma unroll
        for (int i = 0; i < 4; i++) pk0.u[i] = cvtpk(pv[2 * i], pv[2 * i + 1]);
#pragma unroll
        for (int i = 0; i < 4; i++) pk1.u[i] = cvtpk(pv[8 + 2 * i], pv[8 + 2 * i + 1]);
        pa[0] = pk0.v8;
        pa[1] = pk1.v8;
      }

#pragma unroll
      for (int kc = 0; kc < 2; kc++)
#pragma unroll
        for (int dt = 0; dt < 8; dt++) {
          int d = dt * 16 + l15;
          int ps = (kc * 4 + l4) ^ (d & 7);
          bf16x8 vf = *(const bf16x8*)&Vb[d * 64 + ps * 8];
          acc[dt] = __builtin_amdgcn_mfma_f32_16x16x32_bf16(pa[kc], vf, acc[dt], 0, 0, 0);
        }
    }
    asm volatile("s_waitcnt lgkmcnt(0)" ::: "memory");
    __builtin_amdgcn_s_barrier();
  }

  float lr[4];
#pragma unroll
  for (int r = 0; r < 4; r++) lr[r] = __shfl(lsum, l4 * 4 + r);
#pragma unroll
  for (int dt = 0; dt < 8; dt++)
#pragma unroll
    for (int r = 0; r < 4; r++) {
      int row = qw + l4 * 4 + r;
      out[((size_t)(b * Ss) + row) * Hdim + (size_t)h * HDs + dt * 16 + l15] =
          f2bf(acc[dt][r] / lr[r]);
    }
}

// ---------------- launcher ----------------
extern "C" void kernel_launch(void* const* d_in, const int* in_sizes, int n_in,
                              void* d_out, int out_size, void* d_ws, size_t ws_size,
                              hipStream_t stream) {
  const float* hidden = (const float*)d_in[0];
  const int* positions = (const int*)d_in[1];
  const float* wqkv = (const float*)d_in[2];
  const float* wo = (const float*)d_in[3];
  float* out = (float*)d_out;
  char* ws = (char*)d_ws;

  unsigned short* hbf  = (unsigned short*)(ws);
  unsigned short* wT   = (unsigned short*)(ws + 33554432);
  unsigned short* qkvb = (unsigned short*)(ws + 83886080);
  unsigned short* vtb  = (unsigned short*)(ws + 134217728);

  // 1. hidden fp32 -> bf16
  k_f32_to_bf16<<<16384, 256, 0, stream>>>(hidden, hbf, Bb * Ss * Hdim);
  // 2. wqkv [4096][6144] -> wqkvT bf16 [6144][4096]
  k_transpose_bf16<<<dim3(QKV_N / 32, Hdim / 32), dim3(32, 8), 0, stream>>>(wqkv, wT, Hdim, QKV_N);
  // 3. qkv = hidden @ wqkv   (bf16 out), BM=256/BN=128, grid 16x48=768 (%8==0)
  k_gemmv3<1, 256, 128><<<(4096 / 256) * (QKV_N / 128), 256, 0, stream>>>(
      hbf, wT, qkvb, 4096, QKV_N, 4096, QKV_N / 128);
  // 4. RoPE in-place (q scaled by SCALE*log2e)
  k_rope<<<dim3(10, Bb * Ss), 256, 0, stream>>>(qkvb, positions);
  // 5. V -> V^T (kv-permuted) per (b, kv head)
  k_vt<<<dim3(Ss / 32, HDs / 32, Bb * NKV), dim3(32, 8), 0, stream>>>(qkvb, vtb);
  // 6. wo [4096][4096] -> woT bf16
  k_transpose_bf16<<<dim3(Hdim / 32, Hdim / 32), dim3(32, 8), 0, stream>>>(wo, wT, Hdim, Hdim);
  // 7. flash attention v5 -> attn_out (reuses ws0)
  k_attn<<<Bb * NH * (Ss / 128), 512, 0, stream>>>(qkvb, vtb, hbf);
  // 8. out = attn_out @ wo  (fp32 out), BM=128/BN=256, grid 32x16=512 = exactly 2/CU
  k_gemmv3<0, 128, 256><<<(4096 / 128) * (4096 / 256), 256, 0, stream>>>(
      hbf, wT, out, 4096, 4096, 4096, 4096 / 256);
}

// Round 10
// 642.539 us; speedup vs baseline: 1.0616x; 1.0616x over previous
//
#include <hip/hip_runtime.h>
#include <hip/hip_bf16.h>
#include <stdint.h>

// Problem constants (MixtralAttention: B=2, S=2048, H=4096, 32 q-heads, 8 kv-heads, HD=128)
#define Hdim 4096
#define NH 32
#define NKV 8
#define HDs 128
#define Bb 2
#define Ss 2048
#define QKV_N 6144              // NH*HD + 2*NKV*HD
#define SCALEF 0.08838834764831845f   // 128^-0.5
#define LOG2E 1.4426950408889634f
// sliding window = 4096 >= S=2048  ->  pure causal mask

typedef __attribute__((ext_vector_type(4))) float f32x4;
typedef __attribute__((ext_vector_type(8))) short bf16x8;

__device__ __forceinline__ unsigned short f2bf(float f) {
  union { float f; unsigned u; } v; v.f = f;
  unsigned r = v.u + 0x7fffu + ((v.u >> 16) & 1u);   // RNE
  return (unsigned short)(r >> 16);
}
__device__ __forceinline__ float bf2f(unsigned short h) {
  union { unsigned u; float f; } v; v.u = ((unsigned)h) << 16;
  return v.f;
}
__device__ __forceinline__ unsigned cvtpk(float lo, float hi) {
  unsigned r;
  asm("v_cvt_pk_bf16_f32 %0, %1, %2" : "=v"(r) : "v"(lo), "v"(hi));
  return r;
}

#define GLOBAL_AS(p) ((const __attribute__((address_space(1))) void*)(p))
#define LDS_AS(p)    ((__attribute__((address_space(3))) void*)(p))
#define BAR()   __builtin_amdgcn_s_barrier()
// r10 change (single variable vs r8): NO sched_barrier(0) after the lgkmcnt wait.
// ds_reads here are plain C++ loads, so the compiler tracks MFMA dependencies itself
// (rule #18 applies only to inline-asm ds_reads); pinning the schedule at every phase
// boundary is m141's -42% failure mode and was present in both r7 (37%) and r8 (34%).
#define LGKM0() asm volatile("s_waitcnt lgkmcnt(0)" ::: "memory")

// 16-MFMA quadrant: acc[MO..MO+3][NO..NO+1] += a x b  (compile-time MO/NO -> static idx)
template <int MO, int NO>
__device__ __forceinline__ void mm16(f32x4 (&acc)[8][4], const bf16x8 (&a)[4][2],
                                     const bf16x8 (&b)[2][2]) {
#pragma unroll
  for (int m = 0; m < 4; m++)
#pragma unroll
    for (int n = 0; n < 2; n++)
#pragma unroll
      for (int kk = 0; kk < 2; kk++)
        acc[MO + m][NO + n] = __builtin_amdgcn_mfma_f32_16x16x32_bf16(
            a[m][kk], b[n][kk], acc[MO + m][NO + n], 0, 0, 0);
}

// ---------------- fp32 -> bf16 elementwise (hidden_states) ----------------
__global__ void k_f32_to_bf16(const float* __restrict__ src, unsigned short* __restrict__ dst, int n) {
  int i = (blockIdx.x * blockDim.x + threadIdx.x) * 4;
  if (i >= n) return;
  f32x4 v = *(const f32x4*)(src + i);
  uint2 o;
  o.x = (unsigned)f2bf(v.x) | ((unsigned)f2bf(v.y) << 16);
  o.y = (unsigned)f2bf(v.z) | ((unsigned)f2bf(v.w) << 16);
  *(uint2*)(dst + i) = o;
}

// ---------------- fp32 [K][N] -> bf16 [N][K] tile transpose (weights) ----------------
__global__ void k_transpose_bf16(const float* __restrict__ src, unsigned short* __restrict__ dst,
                                 int K, int N) {
  __shared__ unsigned short tile[32][33];
  int n0 = blockIdx.x * 32, k0 = blockIdx.y * 32;
  int tx = threadIdx.x, ty0 = threadIdx.y;
#pragma unroll
  for (int i = 0; i < 4; i++) {
    int ty = ty0 + i * 8;
    tile[ty][tx] = f2bf(src[(size_t)(k0 + ty) * N + n0 + tx]);
  }
  __syncthreads();
#pragma unroll
  for (int i = 0; i < 4; i++) {
    int ty = ty0 + i * 8;
    dst[(size_t)(n0 + ty) * K + k0 + tx] = tile[tx][ty];
  }
}

// ---------------- bf16 GEMM, m201-style 256x256 8-phase schedule ----------------
// Identical to r8 except LGKM0 no longer pins the scheduler (see macro comment).
template <int OUT_BF16>
__global__ __launch_bounds__(512, 2) void k_gemm256(const unsigned short* __restrict__ A,
                                                    const unsigned short* __restrict__ Bt,
                                                    void* __restrict__ C,
                                                    int M, int N, int K, int nbn) {
  __shared__ __align__(16) unsigned short As[2][256 * 64];   // 64 KB
  __shared__ __align__(16) unsigned short Bs[2][256 * 64];   // 64 KB

  int nwg = gridDim.x;
  int orig = blockIdx.x;
  int wg = (orig & 7) * (nwg >> 3) + (orig >> 3);   // XCD swizzle (nwg % 8 == 0)
  int bm = wg / nbn, bn = wg % nbn;

  int t = threadIdx.x, w = t >> 6, lane = t & 63;
  int wm = w >> 2, wn = w & 3;        // wave tile: rows wm*128, cols wn*64
  int l15 = lane & 15, l4 = lane >> 4;

  const unsigned short* Ag = A + (size_t)(bm * 256) * K;
  const unsigned short* Bg = Bt + (size_t)(bn * 256) * K;

  int NKT = K >> 6;

  f32x4 zero = {0.f, 0.f, 0.f, 0.f};
  f32x4 acc[8][4];
#pragma unroll
  for (int m = 0; m < 8; m++)
#pragma unroll
    for (int n = 0; n < 4; n++) acc[m][n] = zero;

  auto stA = [&](int d, int kt, int s) {
    int row = s * 64 + w * 8 + (lane >> 3);
    int gk = ((lane & 7) ^ (row & 7)) << 3;
    __builtin_amdgcn_global_load_lds(GLOBAL_AS(Ag + (size_t)row * K + kt * 64 + gk),
                                     LDS_AS(&As[d][s * 4096 + w * 512]), 16, 0, 0);
  };
  auto stB = [&](int d, int kt, int s) {
    int row = s * 64 + w * 8 + (lane >> 3);
    int gk = ((lane & 7) ^ (row & 7)) << 3;
    __builtin_amdgcn_global_load_lds(GLOBAL_AS(Bg + (size_t)row * K + kt * 64 + gk),
                                     LDS_AS(&Bs[d][s * 4096 + w * 512]), 16, 0, 0);
  };
  auto rdA = [&](int d, int mh, bf16x8 (&a)[4][2]) {
#pragma unroll
    for (int m = 0; m < 4; m++) {
      int row = wm * 128 + mh * 64 + m * 16 + l15;
#pragma unroll
      for (int kk = 0; kk < 2; kk++) {
        int q = kk * 4 + l4;
        a[m][kk] = *(const bf16x8*)&As[d][row * 64 + ((q ^ (row & 7)) << 3)];
      }
    }
  };
  auto rdB = [&](int d, int nh, bf16x8 (&b)[2][2]) {
#pragma unroll
    for (int n = 0; n < 2; n++) {
      int row = wn * 64 + (nh * 2 + n) * 16 + l15;
#pragma unroll
      for (int kk = 0; kk < 2; kk++) {
        int q = kk * 4 + l4;
        b[n][kk] = *(const bf16x8*)&Bs[d][row * 64 + ((q ^ (row & 7)) << 3)];
      }
    }
  };

  // ---- prologue: K0 all 8 slabs, then K1's first 6 (steady-state order) ----
  stA(0, 0, 0); stA(0, 0, 1); stA(0, 0, 2); stA(0, 0, 3);
  stB(0, 0, 0); stB(0, 0, 1); stB(0, 0, 2); stB(0, 0, 3);
  if (NKT > 1) { stA(1, 1, 0); stA(1, 1, 2); stB(1, 1, 0); stB(1, 1, 1); stA(1, 1, 1); stA(1, 1, 3); }
  asm volatile("s_waitcnt vmcnt(6)" ::: "memory");   // K0 fully landed
  BAR();

  bf16x8 af[4][2], bfl[2][2], bfh[2][2];
  for (int i = 0; i < NKT / 2; i++) {
    int kt1 = 2 * i + 1, kt2 = 2 * i + 2, kt3 = 2 * i + 3;
    bool sg = (kt2 < NKT);
    // ---- P1: quad(m0,nlo) of kt0 (buf0) ----
    rdA(0, 0, af); rdB(0, 0, bfl);
    stB(1, kt1, 2); stB(1, kt1, 3);
    BAR(); LGKM0();
    __builtin_amdgcn_s_setprio(1); mm16<0, 0>(acc, af, bfl); __builtin_amdgcn_s_setprio(0);
    BAR();
    // ---- P2: quad(m0,nhi) ----
    rdB(0, 1, bfh);
    if (sg) { stA(0, kt2, 0); stA(0, kt2, 2); }
    BAR(); LGKM0();
    __builtin_amdgcn_s_setprio(1); mm16<0, 2>(acc, af, bfh); __builtin_amdgcn_s_setprio(0);
    BAR();
    // ---- P3: quad(m1,nhi) ----
    rdA(0, 1, af);
    if (sg) { stB(0, kt2, 0); stB(0, kt2, 1); }
    BAR(); LGKM0();
    __builtin_amdgcn_s_setprio(1); mm16<4, 2>(acc, af, bfh); __builtin_amdgcn_s_setprio(0);
    BAR();
    // ---- P4: quad(m1,nlo) (all operands in regs) ----
    if (sg) { stA(0, kt2, 1); stA(0, kt2, 3); }
    BAR();
    __builtin_amdgcn_s_setprio(1); mm16<4, 0>(acc, af, bfl); __builtin_amdgcn_s_setprio(0);
    if (sg) asm volatile("s_waitcnt vmcnt(6)" ::: "memory");
    else    asm volatile("s_waitcnt vmcnt(0)" ::: "memory");
    BAR();
    // ---- P5: quad(m0,nlo) of kt1 (buf1) ----
    rdA(1, 0, af); rdB(1, 0, bfl);
    if (sg) { stB(0, kt2, 2); stB(0, kt2, 3); }
    BAR(); LGKM0();
    __builtin_amdgcn_s_setprio(1); mm16<0, 0>(acc, af, bfl); __builtin_amdgcn_s_setprio(0);
    BAR();
    // ---- P6: quad(m0,nhi) ----
    rdB(1, 1, bfh);
    if (sg) { stA(1, kt3, 0); stA(1, kt3, 2); }
    BAR(); LGKM0();
    __builtin_amdgcn_s_setprio(1); mm16<0, 2>(acc, af, bfh); __builtin_amdgcn_s_setprio(0);
    BAR();
    // ---- P7: quad(m1,nhi) ----
    rdA(1, 1, af);
    if (sg) { stB(1, kt3, 0); stB(1, kt3, 1); }
    BAR(); LGKM0();
    __builtin_amdgcn_s_setprio(1); mm16<4, 2>(acc, af, bfh); __builtin_amdgcn_s_setprio(0);
    BAR();
    // ---- P8: quad(m1,nlo) ----
    if (sg) { stA(1, kt3, 1); stA(1, kt3, 3); }
    BAR();
    __builtin_amdgcn_s_setprio(1); mm16<4, 0>(acc, af, bfl); __builtin_amdgcn_s_setprio(0);
    if (sg) asm volatile("s_waitcnt vmcnt(6)" ::: "memory");
    else    asm volatile("s_waitcnt vmcnt(0)" ::: "memory");
    BAR();
  }

  // epilogue: C/D layout col=lane&15, row=(lane>>4)*4+reg
#pragma unroll
  for (int m = 0; m < 8; m++)
#pragma unroll
    for (int n = 0; n < 4; n++) {
      int col = bn * 256 + wn * 64 + n * 16 + l15;
#pragma unroll
      for (int r = 0; r < 4; r++) {
        int row = bm * 256 + wm * 128 + m * 16 + l4 * 4 + r;
        float v = acc[m][n][r];
        if (OUT_BF16)
          ((unsigned short*)C)[(size_t)row * N + col] = f2bf(v);
        else
          ((float*)C)[(size_t)row * N + col] = v;
      }
    }
}

// ---------------- RoPE (interleaved pairs) in-place on bf16 qkv ------------
__global__ void k_rope(unsigned short* __restrict__ qkv, const int* __restrict__ pos) {
  int bs = blockIdx.y;                       // b*S + s
  int t = threadIdx.x;                       // 256
  int head = blockIdx.x * 4 + (t >> 6);      // 0..39 (0-31 q, 32-39 k)
  int p = t & 63;                            // pair index
  int col;
  float scale;
  if (head < NH) { col = head * HDs + 2 * p; scale = SCALEF * LOG2E; }
  else           { col = NH * HDs + (head - NH) * HDs + 2 * p; scale = 1.f; }
  size_t idx = (size_t)bs * QKV_N + col;
  float x0 = bf2f(qkv[idx]), x1 = bf2f(qkv[idx + 1]);
  float position = (float)pos[bs];
  float inv_freq = exp2f((float)p * -0.2076205059304601f);
  float ang = position * inv_freq;
  float sv, cv;
  sincosf(ang, &sv, &cv);
  float o0 = (x0 * cv - x1 * sv) * scale;
  float o1 = (x1 * cv + x0 * sv) * scale;
  qkv[idx]     = f2bf(o0);
  qkv[idx + 1] = f2bf(o1);
}

// ---------------- V repack: qkv v-part [s][d] -> vt[b][kv][d][s_perm] ---------
__global__ void k_vt(const unsigned short* __restrict__ qkv, unsigned short* __restrict__ vt) {
  __shared__ unsigned short tile[32][33];
  int bkv = blockIdx.z;                 // b*NKV + kvh
  int d0 = blockIdx.y * 32;
  int s0 = blockIdx.x * 32;
  int b = bkv >> 3, kvh = bkv & 7;
  int tx = threadIdx.x, ty0 = threadIdx.y;
  const unsigned short* src = qkv + (size_t)b * Ss * QKV_N + NH * HDs + NKV * HDs + kvh * HDs;
#pragma unroll
  for (int i = 0; i < 4; i++) {
    int ty = ty0 + i * 8;
    tile[ty][tx] = src[(size_t)(s0 + ty) * QKV_N + d0 + tx];
  }
  __syncthreads();
  unsigned short* dst = vt + (size_t)bkv * HDs * Ss;
  int c = s0 + tx;
  int o = c & 63;
  int pcol = (c & ~63) | ((o & 32) | ((o & 12) << 1) | ((o & 16) >> 2) | (o & 3));
#pragma unroll
  for (int i = 0; i < 4; i++) {
    int ty = ty0 + i * 8;
    dst[(size_t)(d0 + ty) * Ss + pcol] = tile[tx][ty];
  }
}

// ---------------- Flash attention v5 (r7, unchanged) -------------------------------
__global__ __launch_bounds__(512, 4) void k_attn(const unsigned short* __restrict__ qkv,
                                                 const unsigned short* __restrict__ vt,
                                                 unsigned short* __restrict__ out) {
  __shared__ __align__(16) unsigned short Ks[2][64 * 128];   // 32 KB
  __shared__ __align__(16) unsigned short Vs[2][128 * 64];   // 32 KB

  int bid = blockIdx.x;
  int qc = 15 - (bid & 15);     // LPT: heavy blocks first
  int h = (bid >> 4) & 31;
  int b = bid >> 9;
  int kvh = h >> 2;             // GROUP = 4
  int t = threadIdx.x;
  int w = t >> 6, lane = t & 63;
  int l15 = lane & 15, l4 = lane >> 4;
  int qb0 = qc * 128;
  int qw = qb0 + w * 16;        // this wave's 16 q rows

  const unsigned short* kbase = qkv + (size_t)b * Ss * QKV_N + NH * HDs + (size_t)kvh * HDs;
  const unsigned short* vbase = vt + ((size_t)(b * NKV + kvh)) * HDs * Ss;

  bf16x8 qf[4];
#pragma unroll
  for (int ch = 0; ch < 4; ch++)
    qf[ch] = *(const bf16x8*)&qkv[((size_t)(b * Ss) + qw + l15) * QKV_N +
                                  (size_t)h * HDs + ch * 32 + l4 * 8];

  f32x4 zero = {0.f, 0.f, 0.f, 0.f};
  f32x4 acc[8];
#pragma unroll
  for (int dt = 0; dt < 8; dt++) acc[dt] = zero;
  float mrun = -1e30f, lsum = 0.f;

  int nkv = qc * 2 + 2;

  auto stageK = [&](int bufi, int kv_) {
#pragma unroll
    for (int i2 = 0; i2 < 2; i2++) {
      int row = i2 * 32 + (t >> 4);
      int sl = (t & 15) ^ (row & 7);
      __builtin_amdgcn_global_load_lds(GLOBAL_AS(kbase + (size_t)(kv_ + row) * QKV_N + sl * 8),
                                       LDS_AS(&Ks[bufi][i2 * 4096 + w * 512]), 16, 0, 0);
    }
  };
  auto stageV = [&](int bufi, int kv_) {
#pragma unroll
    for (int i2 = 0; i2 < 2; i2++) {
      int row = i2 * 64 + (t >> 3);
      int sl = (t & 7) ^ (row & 7);
      __builtin_amdgcn_global_load_lds(GLOBAL_AS(vbase + (size_t)row * Ss + kv_ + sl * 8),
                                       LDS_AS(&Vs[bufi][i2 * 4096 + w * 512]), 16, 0, 0);
    }
  };

  stageK(0, 0); stageV(0, 0);
  for (int it = 0; it < nkv; it++) {
    int kvb = it * 64;
    bool more = (it + 1 < nkv);
    if (more) {
      stageK((it + 1) & 1, kvb + 64);
      stageV((it + 1) & 1, kvb + 64);
      asm volatile("s_waitcnt vmcnt(4)" ::: "memory");
    } else {
      asm volatile("s_waitcnt vmcnt(0)" ::: "memory");
    }
    __builtin_amdgcn_s_barrier();

    if (kvb <= qw + 15) {
      const unsigned short* Kb = Ks[it & 1];
      const unsigned short* Vb = Vs[it & 1];

      f32x4 sacc[4];
#pragma unroll
      for (int kt2 = 0; kt2 < 4; kt2++) sacc[kt2] = zero;
#pragma unroll
      for (int kt2 = 0; kt2 < 4; kt2++) {
        int row = kt2 * 16 + l15;
#pragma unroll
        for (int ch = 0; ch < 4; ch++) {
          int ps = (ch * 4 + l4) ^ (row & 7);
          bf16x8 kf = *(const bf16x8*)&Kb[row * 128 + ps * 8];
          sacc[kt2] = __builtin_amdgcn_mfma_f32_16x16x32_bf16(kf, qf[ch], sacc[kt2], 0, 0, 0);
        }
      }

      int qi = qw + l15;
      bool fullvis = (kvb + 63 <= qw);
      float pv[16];
      float tmax = -1e30f;
#pragma unroll
      for (int kt2 = 0; kt2 < 4; kt2++)
#pragma unroll
        for (int r = 0; r < 4; r++) {
          int kvi = kvb + kt2 * 16 + l4 * 4 + r;
          float v = sacc[kt2][r];
          if (!fullvis) v = (kvi <= qi) ? v : -1e30f;
          pv[kt2 * 4 + r] = v;
          tmax = fmaxf(tmax, v);
        }
      tmax = fmaxf(tmax, __shfl_xor(tmax, 16));
      tmax = fmaxf(tmax, __shfl_xor(tmax, 32));
      if (!__all(tmax - mrun <= 8.f)) {
        float mnew = fmaxf(mrun, tmax);
        float fsc = exp2f(mrun - mnew);
        mrun = mnew;
        lsum *= fsc;
        float fr[4];
#pragma unroll
        for (int r = 0; r < 4; r++) fr[r] = __shfl(fsc, l4 * 4 + r);
#pragma unroll
        for (int dt = 0; dt < 8; dt++)
#pragma unroll
          for (int r = 0; r < 4; r++) acc[dt][r] *= fr[r];
      }
      float rs = 0.f;
#pragma unroll
      for (int i = 0; i < 16; i++) {
        pv[i] = exp2f(pv[i] - mrun);
        rs += pv[i];
      }
      rs += __shfl_xor(rs, 16);
      rs += __shfl_xor(rs, 32);
      lsum += rs;

      bf16x8 pa[2];
      {
        union { unsigned u[4]; bf16x8 v8; } pk0, pk1;
#pragma unroll
        for (int i = 0; i < 4; i++) pk0.u[i] = cvtpk(pv[2 * i], pv[2 * i + 1]);
#pragma unroll
        for (int i = 0; i < 4; i++) pk1.u[i] = cvtpk(pv[8 + 2 * i], pv[8 + 2 * i + 1]);
        pa[0] = pk0.v8;
        pa[1] = pk1.v8;
      }

#pragma unroll
      for (int kc = 0; kc < 2; kc++)
#pragma unroll
        for (int dt = 0; dt < 8; dt++) {
          int d = dt * 16 + l15;
          int ps = (kc * 4 + l4) ^ (d & 7);
          bf16x8 vf = *(const bf16x8*)&Vb[d * 64 + ps * 8];
          acc[dt] = __builtin_amdgcn_mfma_f32_16x16x32_bf16(pa[kc], vf, acc[dt], 0, 0, 0);
        }
    }
    asm volatile("s_waitcnt lgkmcnt(0)" ::: "memory");
    __builtin_amdgcn_s_barrier();
  }

  float lr[4];
#pragma unroll
  for (int r = 0; r < 4; r++) lr[r] = __shfl(lsum, l4 * 4 + r);
#pragma unroll
  for (int dt = 0; dt < 8; dt++)
#pragma unroll
    for (int r = 0; r < 4; r++) {
      int row = qw + l4 * 4 + r;
      out[((size_t)(b * Ss) + row) * Hdim + (size_t)h * HDs + dt * 16 + l15] =
          f2bf(acc[dt][r] / lr[r]);
    }
}

// ---------------- launcher ----------------
extern "C" void kernel_launch(void* const* d_in, const int* in_sizes, int n_in,
                              void* d_out, int out_size, void* d_ws, size_t ws_size,
                              hipStream_t stream) {
  const float* hidden = (const float*)d_in[0];
  const int* positions = (const int*)d_in[1];
  const float* wqkv = (const float*)d_in[2];
  const float* wo = (const float*)d_in[3];
  float* out = (float*)d_out;
  char* ws = (char*)d_ws;

  unsigned short* hbf  = (unsigned short*)(ws);
  unsigned short* wT   = (unsigned short*)(ws + 33554432);
  unsigned short* qkvb = (unsigned short*)(ws + 83886080);
  unsigned short* vtb  = (unsigned short*)(ws + 134217728);

  // 1. hidden fp32 -> bf16
  k_f32_to_bf16<<<16384, 256, 0, stream>>>(hidden, hbf, Bb * Ss * Hdim);
  // 2. wqkv [4096][6144] -> wqkvT bf16 [6144][4096]
  k_transpose_bf16<<<dim3(QKV_N / 32, Hdim / 32), dim3(32, 8), 0, stream>>>(wqkv, wT, Hdim, QKV_N);
  // 3. qkv = hidden @ wqkv   (bf16 out), grid 16x24 = 384 (%8==0)
  k_gemm256<1><<<(4096 / 256) * (QKV_N / 256), 512, 0, stream>>>(hbf, wT, qkvb, 4096, QKV_N, 4096, QKV_N / 256);
  // 4. RoPE in-place (q scaled by SCALE*log2e)
  k_rope<<<dim3(10, Bb * Ss), 256, 0, stream>>>(qkvb, positions);
  // 5. V -> V^T (kv-permuted) per (b, kv head)
  k_vt<<<dim3(Ss / 32, HDs / 32, Bb * NKV), dim3(32, 8), 0, stream>>>(qkvb, vtb);
  // 6. wo [4096][4096] -> woT bf16
  k_transpose_bf16<<<dim3(Hdim / 32, Hdim / 32), dim3(32, 8), 0, stream>>>(wo, wT, Hdim, Hdim);
  // 7. flash attention v5 -> attn_out (reuses ws0)
  k_attn<<<Bb * NH * (Ss / 128), 512, 0, stream>>>(qkvb, vtb, hbf);
  // 8. out = attn_out @ wo  (fp32 out), grid 16x16 = 256 (%8==0)
  k_gemm256<0><<<(4096 / 256) * (4096 / 256), 512, 0, stream>>>(hbf, wT, out, 4096, 4096, 4096, 4096 / 256);
}